// Round 3
// baseline (310.741 us; speedup 1.0000x reference)
//
#include <hip/hip_runtime.h>

// LocalLayer fused via MFMA: a = patches·W^T (hi/lo split bf16, 3 passes),
// e = exp(beta*a) (shift-free softmax), pred = e·W / sum(e) (plain bf16).
// One block per unit, 1024 threads = 16 waves (4 b-groups x 4 o-groups),
// 4 waves/SIMD for latency hiding; W tile double-buffered (2 barriers/tile).

#define Dd 16
#define OUTC 1000
#define Pp 192
#define Bb 64
#define OT 64
#define NT 16
#define THREADS 1024
#define BETA 10.0f

typedef __attribute__((ext_vector_type(8))) short short8;
typedef __attribute__((ext_vector_type(4))) float f32x4;

#define MFMA(a, b, c) __builtin_amdgcn_mfma_f32_16x16x32_bf16((a), (b), (c), 0, 0, 0)

__device__ __forceinline__ unsigned f2bf(float f) {  // RNE f32->bf16 bits
  unsigned u = __float_as_uint(f);
  return (u + 0x7fffu + ((u >> 16) & 1u)) >> 16;
}

// byte addrs, XOR-swizzled 16B blocks (keeps all frag reads ~2-way = free)
__device__ __forceinline__ int paddr(int b, int p) {   // pH/pL [64][192] bf16
  return b * 384 + ((((p) >> 3) ^ (b & 7)) << 4) + ((p) & 7) * 2;
}
__device__ __forceinline__ int waddr(int o, int p) {   // wH/wL [64][192] bf16
  int f = (o & 7) ^ ((o >> 3) & 3);                    // also spreads m2 k-gathers
  return o * 384 + ((((p) >> 3) ^ f) << 4) + ((p) & 7) * 2;
}
__device__ __forceinline__ int eaddr(int b, int o) {   // eS [64][64] bf16
  return b * 128 + ((((o) >> 3) ^ (b & 7)) << 4) + ((o) & 7) * 2;
}

__device__ __forceinline__ void cvt_hilo4(const float4 v, uint2& hi2, uint2& lo2) {
  unsigned h0 = f2bf(v.x), h1 = f2bf(v.y), h2 = f2bf(v.z), h3 = f2bf(v.w);
  float l0 = v.x - __uint_as_float(h0 << 16);
  float l1 = v.y - __uint_as_float(h1 << 16);
  float l2 = v.z - __uint_as_float(h2 << 16);
  float l3 = v.w - __uint_as_float(h3 << 16);
  unsigned g0 = f2bf(l0), g1 = f2bf(l1), g2 = f2bf(l2), g3 = f2bf(l3);
  hi2 = make_uint2(h0 | (h1 << 16), h2 | (h3 << 16));
  lo2 = make_uint2(g0 | (g1 << 16), g2 | (g3 << 16));
}

__global__ __launch_bounds__(THREADS, 4)
void local_layer_mfma2(const float* __restrict__ x,
                       const float* __restrict__ W,
                       float* __restrict__ out) {
  __shared__ unsigned short pH[Bb * Pp];        // 24 KB (persistent)
  __shared__ unsigned short pL[Bb * Pp];        // 24 KB (persistent)
  __shared__ unsigned short wH2[2][OT * Pp];    // 48 KB (double-buffered)
  __shared__ unsigned short wL2[2][OT * Pp];    // 48 KB
  __shared__ unsigned short eSs[Bb * OT];       // 8 KB
  __shared__ float lS[Bb];

  char* pHc = (char*)pH; char* pLc = (char*)pL;
  char* eSc = (char*)eSs;

  const int u = blockIdx.x, uw = u >> 4, uh = u & 15;
  const int tid = threadIdx.x;
  const int wv = tid >> 6, lane = tid & 63;
  const int lr = lane & 15, lg = lane >> 4;
  const int mq = wv & 3;            // b-group: rows 16*mq .. +15
  const int ow = wv >> 2;           // 0..3: m1 o-16 group / m2 p-48 group
  const int bB = 16 * mq;

  const float* Wu = W + (size_t)u * (OUTC * Pp);

  if (tid < Bb) lS[tid] = 0.f;

  // ---- prefetch W tile 0 into regs (3 float4/thread) ----
  float4 R[3];
#pragma unroll
  for (int k = 0; k < 3; ++k) {
    int i4 = tid + THREADS * k;
    int o = i4 / 48, p = (i4 % 48) * 4;
    R[k] = *reinterpret_cast<const float4*>(Wu + o * Pp + p);
  }

  // ---- stage patches -> pH/pL (hi/lo bf16) ----
#pragma unroll
  for (int k = 0; k < 3; ++k) {
    int i4 = tid + THREADS * k;
    int b = i4 / 48, q = i4 % 48, p = q * 4;
    int c = p >> 6, kh = (p >> 3) & 7, kw = p & 7;
    float4 v = *reinterpret_cast<const float4*>(
        x + ((size_t)((b * 3 + c) * 128 + uw * 8 + kh) * 128 + uh * 8 + kw));
    uint2 hi2, lo2;
    cvt_hilo4(v, hi2, lo2);
    *reinterpret_cast<uint2*>(pHc + paddr(b, p)) = hi2;
    *reinterpret_cast<uint2*>(pLc + paddr(b, p)) = lo2;
  }

  // ---- convert+write W tile 0 into buf 0 ----
  {
    char* wHc = (char*)wH2[0];
    char* wLc = (char*)wL2[0];
#pragma unroll
    for (int k = 0; k < 3; ++k) {
      int i4 = tid + THREADS * k;
      int o = i4 / 48, p = (i4 % 48) * 4;
      uint2 hi2, lo2;
      cvt_hilo4(R[k], hi2, lo2);
      *reinterpret_cast<uint2*>(wHc + waddr(o, p)) = hi2;
      *reinterpret_cast<uint2*>(wLc + waddr(o, p)) = lo2;
    }
  }
  __syncthreads();   // patches + tile0 visible

  // ---- hoist patch-hi A-frags (tile-invariant); patch-lo stays in LDS ----
  short8 pa_h[6];
#pragma unroll
  for (int ks = 0; ks < 6; ++ks)
    pa_h[ks] = *reinterpret_cast<const short8*>(pHc + paddr(bB + lr, 32 * ks + 8 * lg));

  f32x4 pacc[3];
#pragma unroll
  for (int f = 0; f < 3; ++f) pacc[f] = (f32x4){0.f, 0.f, 0.f, 0.f};
  float lPart[4] = {0.f, 0.f, 0.f, 0.f};

  for (int t = 0; t < NT; ++t) {
    char* wHc = (char*)wH2[t & 1];
    char* wLc = (char*)wL2[t & 1];

    // ---- issue loads for tile t+1 (consumed after m2) ----
    if (t + 1 < NT) {
#pragma unroll
      for (int k = 0; k < 3; ++k) {
        int i4 = tid + THREADS * k;
        int o = i4 / 48, p = (i4 % 48) * 4;
        int o_g = (t + 1) * OT + o;
        R[k] = (o_g < OUTC)
                   ? *reinterpret_cast<const float4*>(Wu + (size_t)o_g * Pp + p)
                   : make_float4(0.f, 0.f, 0.f, 0.f);
      }
    }

    // ---- m1: a[16 b-rows][16 o-cols] over K=192, hi/lo 3 passes ----
    f32x4 acc = (f32x4){0.f, 0.f, 0.f, 0.f};
#pragma unroll
    for (int ks = 0; ks < 6; ++ks) {
      const int ko = 32 * ks + 8 * lg;
      short8 wbh = *reinterpret_cast<const short8*>(wHc + waddr(16 * ow + lr, ko));
      short8 wbl = *reinterpret_cast<const short8*>(wLc + waddr(16 * ow + lr, ko));
      short8 pal = *reinterpret_cast<const short8*>(pLc + paddr(bB + lr, ko));
      acc = MFMA(pa_h[ks], wbh, acc);
      acc = MFMA(pa_h[ks], wbl, acc);
      acc = MFMA(pal, wbh, acc);
    }

    // ---- e = exp(beta*a), zero invalid o, write eS, accumulate lPart ----
    {
      const int o_g = t * OT + 16 * ow + lr;
      const bool valid = (o_g < OUTC);
#pragma unroll
      for (int j = 0; j < 4; ++j) {
        float e = valid ? __expf(BETA * acc[j]) : 0.f;
        lPart[j] += e;
        *reinterpret_cast<unsigned short*>(
            eSc + eaddr(bB + 4 * lg + j, 16 * ow + lr)) = (unsigned short)f2bf(e);
      }
    }
    __syncthreads();   // BAR1: eS complete

    // ---- m2: pred[16 b-rows][48 p-cols] += e·W ----
    short8 ea[2];
#pragma unroll
    for (int ks2 = 0; ks2 < 2; ++ks2)
      ea[ks2] = *reinterpret_cast<const short8*>(
          eSc + eaddr(bB + lr, 32 * ks2 + 8 * lg));

#pragma unroll
    for (int f = 0; f < 3; ++f) {
      const int p = 48 * ow + 16 * f + lr;
#pragma unroll
      for (int ks2 = 0; ks2 < 2; ++ks2) {
        short8 wb;
#pragma unroll
        for (int e8 = 0; e8 < 8; ++e8)
          wb[e8] = *reinterpret_cast<const short*>(
              wHc + waddr(32 * ks2 + 8 * lg + e8, p));
        pacc[f] = MFMA(ea[ks2], wb, pacc[f]);
      }
    }

    // ---- convert+write tile t+1 into the other buffer (overlaps with m2 waves) ----
    if (t + 1 < NT) {
      char* nH = (char*)wH2[(t + 1) & 1];
      char* nL = (char*)wL2[(t + 1) & 1];
#pragma unroll
      for (int k = 0; k < 3; ++k) {
        int i4 = tid + THREADS * k;
        int o = i4 / 48, p = (i4 % 48) * 4;
        uint2 hi2, lo2;
        cvt_hilo4(R[k], hi2, lo2);
        *reinterpret_cast<uint2*>(nH + waddr(o, p)) = hi2;
        *reinterpret_cast<uint2*>(nL + waddr(o, p)) = lo2;
      }
    }
    __syncthreads();   // BAR2: next tile visible; eS free for overwrite
  }

  // ---- softmax denominators: reduce lPart over the 16 lr lanes ----
#pragma unroll
  for (int j = 0; j < 4; ++j) {
    float v = lPart[j];
    v += __shfl_xor(v, 1, 16);
    v += __shfl_xor(v, 2, 16);
    v += __shfl_xor(v, 4, 16);
    v += __shfl_xor(v, 8, 16);
    if (lr == 0) atomicAdd(&lS[bB + 4 * lg + j], v);
  }
  __syncthreads();

  // ---- epilogue: out = pacc / l, scatter to image layout ----
  float inv[4];
#pragma unroll
  for (int j = 0; j < 4; ++j) inv[j] = 1.f / lS[bB + 4 * lg + j];
#pragma unroll
  for (int f = 0; f < 3; ++f) {
    const int p = 48 * ow + 16 * f + lr;
    const int c = p >> 6, kh = (p >> 3) & 7, kw = p & 7;
#pragma unroll
    for (int j = 0; j < 4; ++j) {
      const int b = bB + 4 * lg + j;
      out[((size_t)((b * 3 + c) * 128 + uw * 8 + kh)) * 128 + uh * 8 + kw] =
          pacc[f][j] * inv[j];
    }
  }
}

extern "C" void kernel_launch(void* const* d_in, const int* in_sizes, int n_in,
                              void* d_out, int out_size, void* d_ws, size_t ws_size,
                              hipStream_t stream) {
  const float* x = (const float*)d_in[0];
  const float* W = (const float*)d_in[1];
  float* out = (float*)d_out;
  hipLaunchKernelGGL(local_layer_mfma2, dim3(Dd * Dd), dim3(THREADS), 0, stream,
                     x, W, out);
}